// Round 14
// baseline (267.857 us; speedup 1.0000x reference)
//
#include <hip/hip_runtime.h>

#define N_NODES 50000
#define N_EDGES 800000
#define D 128
#define NGRAPH 50

typedef unsigned int uint32;
typedef unsigned short u16;
typedef __attribute__((ext_vector_type(8))) short short8;
typedef __attribute__((ext_vector_type(4))) float f32x4;

__device__ inline float bf_lo(uint32 u) { union { uint32 u; float f; } c; c.u = u << 16; return c.f; }
__device__ inline float bf_hi(uint32 u) { union { uint32 u; float f; } c; c.u = u & 0xffff0000u; return c.f; }
__device__ inline u16 f2bf(float f) {  // RNE
  union { float f; uint32 u; } c; c.f = f;
  uint32 r = (c.u + 0x7fffu + ((c.u >> 16) & 1u)) >> 16;
  return (u16)r;
}

// ---------------- fused init: deg=0, WT transpose ----------------
__global__ void k_init(int* __restrict__ deg, const float* __restrict__ Wc,
                       u16* __restrict__ WT) {
  int i = blockIdx.x * 256 + threadIdx.x;
  if (i < N_NODES) deg[i] = 0;
  if (i < 3 * 128 * 128) {  // WT[l][n][k] = Wc[l][k][n], bf16
    int layer = i >> 14, rem = i & 16383;
    int n = rem >> 7, k = rem & 127;
    WT[i] = f2bf(Wc[layer * 16384 + k * 128 + n]);
  }
}

// ---------------- degree + CSR fill, XCD-partitioned by dst range ----------------
__global__ void k_degfill(const int* __restrict__ src, const int* __restrict__ dst,
                          int* __restrict__ deg, u16* __restrict__ csr) {
  int part = blockIdx.x & 7;
  int e = (blockIdx.x >> 3) * 256 + threadIdx.x;
  if (e < N_EDGES) {
    int d = dst[e];
    if (d / 6250 == part) {  // 0..49999 -> 8 equal ranges
      int r = atomicAdd(&deg[d], 1);  // max degree ~40 << 64 (Poisson(16))
      csr[(d << 6) + r] = (u16)src[e];
    }
  }
}

// ---------------- prescale: xs = bf16(dinv * x), uint4 per 8 channels ----------------
__global__ void k_prescale(const float4* __restrict__ x, const int* __restrict__ deg,
                           uint4* __restrict__ xs) {
  int i = blockIdx.x * 256 + threadIdx.x;
  if (i < N_NODES * 16) {
    int node = i >> 4;
    float di = rsqrtf((float)deg[node] + 1.0f);
    float4 v0 = x[(size_t)i * 2];
    float4 v1 = x[(size_t)i * 2 + 1];
    uint4 o;
    o.x = ((uint32)f2bf(di * v0.y) << 16) | f2bf(di * v0.x);
    o.y = ((uint32)f2bf(di * v0.w) << 16) | f2bf(di * v0.z);
    o.z = ((uint32)f2bf(di * v1.y) << 16) | f2bf(di * v1.x);
    o.w = ((uint32)f2bf(di * v1.w) << 16) | f2bf(di * v1.z);
    xs[i] = o;
  }
}

// ---------------- fused layer: 16 nodes/block, 4 nodes/wave gather, MFMA, epilogue ----
#define ACC8(A, u) do { \
    A##0 += bf_lo((u).x); A##1 += bf_hi((u).x); A##2 += bf_lo((u).y); A##3 += bf_hi((u).y); \
    A##4 += bf_lo((u).z); A##5 += bf_hi((u).z); A##6 += bf_lo((u).w); A##7 += bf_hi((u).w); } while (0)

#define RED2(v) do { v += __shfl_xor(v, 16); v += __shfl_xor(v, 32); } while (0)

template <int PRESCALE_OUT>
__global__ __launch_bounds__(256) void k_layer(const uint4* __restrict__ xs,
                                               const int* __restrict__ deg,
                                               const u16* __restrict__ csr,
                                               const u16* __restrict__ WT,
                                               const float* __restrict__ bc,
                                               u16* __restrict__ xo) {
  __shared__ u16 sa[16][136];  // aggregated A-tile (bf16)
  __shared__ u16 so[16][136];  // output staging
  int t = threadIdx.x;
  int wave = t >> 6, l = t & 63;
  int q = l >> 4, c = l & 15;  // quarter (edge slot), 16B channel-group
  int r0 = blockIdx.x * 16;    // 50000 = 3125 * 16, no tail

  // ---- phase 1: wave aggregates its 4 nodes ----
  for (int n = 0; n < 4; ++n) {
    int i = r0 + wave * 4 + n;
    int cnt = deg[i];
    float a0 = 0.f, a1 = 0.f, a2 = 0.f, a3 = 0.f, a4 = 0.f, a5 = 0.f, a6 = 0.f, a7 = 0.f;
    if (q == 0) {  // self-loop term
      uint4 su = xs[(size_t)i * 16 + c];
      ACC8(a, su);
    }
    int myidx = (l < cnt) ? (int)csr[(i << 6) + l] : 0;
    int nq = (cnt + 3) >> 2;
#pragma unroll 4
    for (int j = 0; j < nq; ++j) {
      int idx = 4 * j + q;
      int s = __shfl(myidx, idx < cnt ? idx : 0);
      uint4 u = xs[(size_t)s * 16 + c];
      if (idx < cnt) ACC8(a, u);
    }
    RED2(a0); RED2(a1); RED2(a2); RED2(a3); RED2(a4); RED2(a5); RED2(a6); RED2(a7);
    if (q == 0) {
      uint4 o;
      o.x = ((uint32)f2bf(a1) << 16) | f2bf(a0);
      o.y = ((uint32)f2bf(a3) << 16) | f2bf(a2);
      o.z = ((uint32)f2bf(a5) << 16) | f2bf(a4);
      o.w = ((uint32)f2bf(a7) << 16) | f2bf(a6);
      *reinterpret_cast<uint4*>(&sa[wave * 4 + n][c * 8]) = o;
    }
  }
  __syncthreads();

  // ---- phase 2: MFMA — wave handles output-channel blocks cc = 2*wave, 2*wave+1 ----
  const short8* B8 = reinterpret_cast<const short8*>(WT);
  f32x4 acc[2] = {};
#pragma unroll
  for (int k0 = 0; k0 < 4; ++k0) {
    short8 a = *reinterpret_cast<const short8*>(&sa[c][(k0 * 4 + q) * 8]);
#pragma unroll
    for (int m = 0; m < 2; ++m) {
      int cc = wave * 2 + m;
      short8 b = B8[(cc * 16 + c) * 16 + k0 * 4 + q];
      acc[m] = __builtin_amdgcn_mfma_f32_16x16x32_bf16(a, b, acc[m], 0, 0, 0);
    }
  }

  // ---- phase 3: epilogue. C/D layout: col = c (within cc block), row = q*4 + j ----
  float dj[4];
#pragma unroll
  for (int j = 0; j < 4; ++j) {
    dj[j] = rsqrtf((float)deg[r0 + q * 4 + j] + 1.0f);
  }
#pragma unroll
  for (int m = 0; m < 2; ++m) {
    int cc = wave * 2 + m;
    float bcv = bc[cc * 16 + c];
#pragma unroll
    for (int j = 0; j < 4; ++j) {
      float r = fmaxf(fmaf(dj[j], acc[m][j], bcv), 0.f);
      if (PRESCALE_OUT) r *= dj[j];
      so[q * 4 + j][cc * 16 + c] = f2bf(r);
    }
  }
  __syncthreads();

  // ---- phase 4: coalesced store ----
  int rr = t >> 4, ch = t & 15;
  *reinterpret_cast<uint4*>(&xo[(size_t)(r0 + rr) * 128 + ch * 8]) =
      *reinterpret_cast<const uint4*>(&so[rr][ch * 8]);
}

// ---------------- head: global_add_pool (direct bf16 reads) + 3-layer MLP ----------
__global__ __launch_bounds__(128) void k_head(const u16* __restrict__ xb,
                                              const int* __restrict__ batch,
                                              const float* __restrict__ Wf,
                                              const float* __restrict__ bf,
                                              float* __restrict__ out) {
  __shared__ float row[D];
  int g = blockIdx.x, c = threadIdx.x;

  // graph bounds via binary search on sorted batch (uniform across threads)
  int lo = 0, hi = N_NODES;
  while (lo < hi) { int m = (lo + hi) >> 1; if (batch[m] < g) lo = m + 1; else hi = m; }
  int s = lo;
  lo = 0; hi = N_NODES;
  while (lo < hi) { int m = (lo + hi) >> 1; if (batch[m] < g + 1) lo = m + 1; else hi = m; }
  int e = lo;

  // pool: thread c sums channel c over rows [s,e); 128 threads -> 256B/row coalesced
  float acc = 0.f;
  int n = s;
  for (; n + 4 <= e; n += 4) {
    float v0 = bf_lo((uint32)xb[(size_t)(n + 0) * D + c]);
    float v1 = bf_lo((uint32)xb[(size_t)(n + 1) * D + c]);
    float v2 = bf_lo((uint32)xb[(size_t)(n + 2) * D + c]);
    float v3 = bf_lo((uint32)xb[(size_t)(n + 3) * D + c]);
    acc += v0 + v1 + v2 + v3;
  }
  for (; n < e; ++n) acc += bf_lo((uint32)xb[(size_t)n * D + c]);
  row[c] = acc;
  __syncthreads();

  // 3-layer MLP
  for (int l = 0; l < 3; ++l) {
    const float* W = Wf + l * D * D;
    float sum = bf[l * D + c];
    for (int k = 0; k < D; ++k) sum = fmaf(row[k], W[k * D + c], sum);
    sum = fmaxf(sum, 0.f);
    __syncthreads();
    row[c] = sum;
    __syncthreads();
  }
  out[g * D + c] = row[c];
}

extern "C" void kernel_launch(void* const* d_in, const int* in_sizes, int n_in,
                              void* d_out, int out_size, void* d_ws, size_t ws_size,
                              hipStream_t stream) {
  const float* x   = (const float*)d_in[0];
  const int*   ei  = (const int*)d_in[1];
  const int* batch = (const int*)d_in[2];
  const float* Wc  = (const float*)d_in[3];
  const float* bc  = (const float*)d_in[4];
  const float* Wf  = (const float*)d_in[5];
  const float* bf  = (const float*)d_in[6];
  float* out = (float*)d_out;
  const int* src = ei;
  const int* dst = ei + N_EDGES;

  char* ws = (char*)d_ws;
  size_t o = 0;
  auto take = [&](size_t b) -> void* {
    void* p = ws + o;
    o = (o + b + 255) & ~(size_t)255;
    return p;
  };
  int*  deg    = (int*)take(N_NODES * 4);
  u16*  WT     = (u16*)take((size_t)3 * D * D * 2);
  u16*  csr    = (u16*)take((size_t)N_NODES * 64 * 2);  // implicit offs = 64*i
  u16*  xsA    = (u16*)take((size_t)N_NODES * D * 2);
  u16*  xsB    = (u16*)take((size_t)N_NODES * D * 2);
  (void)ws_size; (void)in_sizes; (void)n_in; (void)out_size;

  const int NB = (N_NODES + 255) / 256;
  k_init<<<NB, 256, 0, stream>>>(deg, Wc, WT);
  k_degfill<<<8 * ((N_EDGES + 255) / 256), 256, 0, stream>>>(src, dst, deg, csr);
  k_prescale<<<(N_NODES * 16 + 255) / 256, 256, 0, stream>>>((const float4*)x, deg, (uint4*)xsA);

  const int GB = N_NODES / 16;  // 3125
  k_layer<1><<<GB, 256, 0, stream>>>((const uint4*)xsA, deg, csr, WT + 0 * D * D, bc + 0 * D, xsB);
  k_layer<1><<<GB, 256, 0, stream>>>((const uint4*)xsB, deg, csr, WT + 1 * D * D, bc + 1 * D, xsA);
  k_layer<0><<<GB, 256, 0, stream>>>((const uint4*)xsA, deg, csr, WT + 2 * D * D, bc + 2 * D, xsB);

  k_head<<<NGRAPH, 128, 0, stream>>>(xsB, batch, Wf, bf, out);
}

// Round 15
// 204.720 us; speedup vs baseline: 1.3084x; 1.3084x over previous
//
#include <hip/hip_runtime.h>

#define N_NODES 50000
#define N_EDGES 800000
#define D 128
#define NGRAPH 50

typedef unsigned int uint32;
typedef unsigned short u16;
typedef __attribute__((ext_vector_type(8))) short short8;
typedef __attribute__((ext_vector_type(4))) float f32x4;

__device__ inline float bf_lo(uint32 u) { union { uint32 u; float f; } c; c.u = u << 16; return c.f; }
__device__ inline float bf_hi(uint32 u) { union { uint32 u; float f; } c; c.u = u & 0xffff0000u; return c.f; }
__device__ inline u16 f2bf(float f) {  // RNE
  union { float f; uint32 u; } c; c.f = f;
  uint32 r = (c.u + 0x7fffu + ((c.u >> 16) & 1u)) >> 16;
  return (u16)r;
}

// ---------------- fused init: deg=0, WT transpose, graph bounds ----------------
__global__ void k_init(int* __restrict__ deg, const float* __restrict__ Wc,
                       u16* __restrict__ WT, const int* __restrict__ batch,
                       int* __restrict__ gstart) {
  int i = blockIdx.x * 256 + threadIdx.x;
  if (i < N_NODES) deg[i] = 0;
  if (i < 3 * 128 * 128) {  // WT[l][n][k] = Wc[l][k][n], bf16
    int layer = i >> 14, rem = i & 16383;
    int n = rem >> 7, k = rem & 127;
    WT[i] = f2bf(Wc[layer * 16384 + k * 128 + n]);
  }
  if (i <= NGRAPH) {
    int lo = 0, hi = N_NODES;
    while (lo < hi) {
      int mid = (lo + hi) >> 1;
      if (batch[mid] < i) lo = mid + 1; else hi = mid;
    }
    gstart[i] = lo;
  }
}

// ---------------- degree + CSR fill, XCD-partitioned by dst range ----------------
__global__ void k_degfill(const int* __restrict__ src, const int* __restrict__ dst,
                          int* __restrict__ deg, u16* __restrict__ csr) {
  int part = blockIdx.x & 7;
  int e = (blockIdx.x >> 3) * 256 + threadIdx.x;
  if (e < N_EDGES) {
    int d = dst[e];
    if (d / 6250 == part) {  // 0..49999 -> 8 equal ranges
      int r = atomicAdd(&deg[d], 1);  // max degree ~40 << 64 (Poisson(16))
      csr[(d << 6) + r] = (u16)src[e];
    }
  }
}

// ---------------- prescale: xs = bf16(dinv * x), uint4 per 8 channels ----------------
__global__ void k_prescale(const float4* __restrict__ x, const int* __restrict__ deg,
                           uint4* __restrict__ xs) {
  int i = blockIdx.x * 256 + threadIdx.x;
  if (i < N_NODES * 16) {
    int node = i >> 4;
    float di = rsqrtf((float)deg[node] + 1.0f);
    float4 v0 = x[(size_t)i * 2];
    float4 v1 = x[(size_t)i * 2 + 1];
    uint4 o;
    o.x = ((uint32)f2bf(di * v0.y) << 16) | f2bf(di * v0.x);
    o.y = ((uint32)f2bf(di * v0.w) << 16) | f2bf(di * v0.z);
    o.z = ((uint32)f2bf(di * v1.y) << 16) | f2bf(di * v1.x);
    o.w = ((uint32)f2bf(di * v1.w) << 16) | f2bf(di * v1.z);
    xs[i] = o;
  }
}

// ---------------- fused layer: 16 nodes/block, 4 nodes/wave gather, MFMA, epilogue ----
#define ACC8(A, u) do { \
    A##0 += bf_lo((u).x); A##1 += bf_hi((u).x); A##2 += bf_lo((u).y); A##3 += bf_hi((u).y); \
    A##4 += bf_lo((u).z); A##5 += bf_hi((u).z); A##6 += bf_lo((u).w); A##7 += bf_hi((u).w); } while (0)

#define RED2(v) do { v += __shfl_xor(v, 16); v += __shfl_xor(v, 32); } while (0)

template <int PRESCALE_OUT>
__global__ __launch_bounds__(256) void k_layer(const uint4* __restrict__ xs,
                                               const int* __restrict__ deg,
                                               const u16* __restrict__ csr,
                                               const u16* __restrict__ WT,
                                               const float* __restrict__ bc,
                                               u16* __restrict__ xo) {
  __shared__ u16 sa[16][136];  // aggregated A-tile (bf16)
  __shared__ u16 so[16][136];  // output staging
  int t = threadIdx.x;
  int wave = t >> 6, l = t & 63;
  int q = l >> 4, c = l & 15;  // quarter (edge slot), 16B channel-group
  int r0 = blockIdx.x * 16;    // 50000 = 3125 * 16, no tail

  // ---- phase 1: wave aggregates its 4 nodes ----
  for (int n = 0; n < 4; ++n) {
    int i = r0 + wave * 4 + n;
    int cnt = deg[i];
    float a0 = 0.f, a1 = 0.f, a2 = 0.f, a3 = 0.f, a4 = 0.f, a5 = 0.f, a6 = 0.f, a7 = 0.f;
    if (q == 0) {  // self-loop term
      uint4 su = xs[(size_t)i * 16 + c];
      ACC8(a, su);
    }
    int myidx = (l < cnt) ? (int)csr[(i << 6) + l] : 0;
    int nq = (cnt + 3) >> 2;
#pragma unroll 4
    for (int j = 0; j < nq; ++j) {
      int idx = 4 * j + q;
      int s = __shfl(myidx, idx < cnt ? idx : 0);
      uint4 u = xs[(size_t)s * 16 + c];
      if (idx < cnt) ACC8(a, u);
    }
    RED2(a0); RED2(a1); RED2(a2); RED2(a3); RED2(a4); RED2(a5); RED2(a6); RED2(a7);
    if (q == 0) {
      uint4 o;
      o.x = ((uint32)f2bf(a1) << 16) | f2bf(a0);
      o.y = ((uint32)f2bf(a3) << 16) | f2bf(a2);
      o.z = ((uint32)f2bf(a5) << 16) | f2bf(a4);
      o.w = ((uint32)f2bf(a7) << 16) | f2bf(a6);
      *reinterpret_cast<uint4*>(&sa[wave * 4 + n][c * 8]) = o;
    }
  }
  __syncthreads();

  // ---- phase 2: MFMA — wave handles output-channel blocks cc = 2*wave, 2*wave+1 ----
  const short8* B8 = reinterpret_cast<const short8*>(WT);
  f32x4 acc[2] = {};
#pragma unroll
  for (int k0 = 0; k0 < 4; ++k0) {
    short8 a = *reinterpret_cast<const short8*>(&sa[c][(k0 * 4 + q) * 8]);
#pragma unroll
    for (int m = 0; m < 2; ++m) {
      int cc = wave * 2 + m;
      short8 b = B8[(cc * 16 + c) * 16 + k0 * 4 + q];
      acc[m] = __builtin_amdgcn_mfma_f32_16x16x32_bf16(a, b, acc[m], 0, 0, 0);
    }
  }

  // ---- phase 3: epilogue. C/D layout: col = c (within cc block), row = q*4 + j ----
  float dj[4];
#pragma unroll
  for (int j = 0; j < 4; ++j) {
    dj[j] = rsqrtf((float)deg[r0 + q * 4 + j] + 1.0f);
  }
#pragma unroll
  for (int m = 0; m < 2; ++m) {
    int cc = wave * 2 + m;
    float bcv = bc[cc * 16 + c];
#pragma unroll
    for (int j = 0; j < 4; ++j) {
      float r = fmaxf(fmaf(dj[j], acc[m][j], bcv), 0.f);
      if (PRESCALE_OUT) r *= dj[j];
      so[q * 4 + j][cc * 16 + c] = f2bf(r);
    }
  }
  __syncthreads();

  // ---- phase 4: coalesced store ----
  int rr = t >> 4, ch = t & 15;
  *reinterpret_cast<uint4*>(&xo[(size_t)(r0 + rr) * 128 + ch * 8]) =
      *reinterpret_cast<const uint4*>(&so[rr][ch * 8]);
}

// ---------------- pooling from bf16 rows: partial sums, no atomics, no init ----------
__global__ __launch_bounds__(256) void k_pool(const uint32* __restrict__ xb,
                                              const int* __restrict__ gstart,
                                              float* __restrict__ pp) {
  __shared__ float2 red[4][64];
  int g = blockIdx.x, ch = blockIdx.y;
  int s = gstart[g], e = gstart[g + 1];
  long len = e - s;
  int cs = s + (int)(len * ch / 8);
  int ce = s + (int)(len * (ch + 1) / 8);
  int sub = threadIdx.x >> 6, l = threadIdx.x & 63;
  float2 acc = make_float2(0.f, 0.f);
  for (int n = cs + sub; n < ce; n += 4) {
    uint32 v = xb[(size_t)n * 64 + l];
    acc.x += bf_lo(v);
    acc.y += bf_hi(v);
  }
  red[sub][l] = acc;
  __syncthreads();
  if (sub == 0) {
    float2 a = red[0][l];
    a.x += red[1][l].x + red[2][l].x + red[3][l].x;
    a.y += red[1][l].y + red[2][l].y + red[3][l].y;
    pp[(ch * NGRAPH + g) * D + 2 * l] = a.x;
    pp[(ch * NGRAPH + g) * D + 2 * l + 1] = a.y;
  }
}

// ---------------- MLP head (sums the 8 pooling partials) ----------------
__global__ __launch_bounds__(128) void k_fc(const float* __restrict__ pp,
                                            const float* __restrict__ Wf,
                                            const float* __restrict__ bf,
                                            float* __restrict__ out) {
  __shared__ float row[D];
  int g = blockIdx.x, c = threadIdx.x;
  float v = 0.f;
#pragma unroll
  for (int ch = 0; ch < 8; ++ch) v += pp[(ch * NGRAPH + g) * D + c];
  row[c] = v;
  __syncthreads();
  for (int l = 0; l < 3; ++l) {
    const float* W = Wf + l * D * D;
    float s = bf[l * D + c];
    for (int k = 0; k < D; ++k) s = fmaf(row[k], W[k * D + c], s);
    s = fmaxf(s, 0.f);
    __syncthreads();
    row[c] = s;
    __syncthreads();
  }
  out[g * D + c] = row[c];
}

extern "C" void kernel_launch(void* const* d_in, const int* in_sizes, int n_in,
                              void* d_out, int out_size, void* d_ws, size_t ws_size,
                              hipStream_t stream) {
  const float* x   = (const float*)d_in[0];
  const int*   ei  = (const int*)d_in[1];
  const int* batch = (const int*)d_in[2];
  const float* Wc  = (const float*)d_in[3];
  const float* bc  = (const float*)d_in[4];
  const float* Wf  = (const float*)d_in[5];
  const float* bf  = (const float*)d_in[6];
  float* out = (float*)d_out;
  const int* src = ei;
  const int* dst = ei + N_EDGES;

  char* ws = (char*)d_ws;
  size_t o = 0;
  auto take = [&](size_t b) -> void* {
    void* p = ws + o;
    o = (o + b + 255) & ~(size_t)255;
    return p;
  };
  int*  deg    = (int*)take(N_NODES * 4);
  int*  gstart = (int*)take(64 * 4);
  u16*  WT     = (u16*)take((size_t)3 * D * D * 2);
  u16*  csr    = (u16*)take((size_t)N_NODES * 64 * 2);  // implicit offs = 64*i
  u16*  xsA    = (u16*)take((size_t)N_NODES * D * 2);
  u16*  xsB    = (u16*)take((size_t)N_NODES * D * 2);
  float* pp    = (float*)take((size_t)8 * NGRAPH * D * 4);
  (void)ws_size; (void)in_sizes; (void)n_in; (void)out_size;

  const int NB = (N_NODES + 255) / 256;
  k_init<<<NB, 256, 0, stream>>>(deg, Wc, WT, batch, gstart);
  k_degfill<<<8 * ((N_EDGES + 255) / 256), 256, 0, stream>>>(src, dst, deg, csr);
  k_prescale<<<(N_NODES * 16 + 255) / 256, 256, 0, stream>>>((const float4*)x, deg, (uint4*)xsA);

  const int GB = N_NODES / 16;  // 3125
  // layer 0: xsA -> xsB (prescaled out)
  k_layer<1><<<GB, 256, 0, stream>>>((const uint4*)xsA, deg, csr, WT + 0 * D * D, bc + 0 * D, xsB);
  // layer 1: xsB -> xsA (prescaled out)
  k_layer<1><<<GB, 256, 0, stream>>>((const uint4*)xsB, deg, csr, WT + 1 * D * D, bc + 1 * D, xsA);
  // layer 2: xsA -> xsB (raw out for pooling)
  k_layer<0><<<GB, 256, 0, stream>>>((const uint4*)xsA, deg, csr, WT + 2 * D * D, bc + 2 * D, xsB);

  k_pool<<<dim3(NGRAPH, 8), 256, 0, stream>>>((const uint32*)xsB, gstart, pp);
  k_fc<<<NGRAPH, 128, 0, stream>>>(pp, Wf, bf, out);
}